// Round 6
// baseline (215.048 us; speedup 1.0000x reference)
//
#include <hip/hip_runtime.h>

#define NS 128
#define NRAYS 8192

typedef unsigned short u16;
typedef unsigned int   u32;
typedef unsigned short u16x8 __attribute__((ext_vector_type(8)));
typedef __bf16 b16x8 __attribute__((ext_vector_type(8)));
typedef float f32x4 __attribute__((ext_vector_type(4)));
typedef _Float16 h16x2 __attribute__((ext_vector_type(2)));
typedef unsigned int u32x4 __attribute__((ext_vector_type(4)));

__device__ __forceinline__ float clampf(float x, float lo, float hi) {
    return fminf(fmaxf(x, lo), hi);
}

// f32 -> bf16 bits via native cast (single v_cvt, RNE)
__device__ __forceinline__ u16 f2bf(float f) {
    return __builtin_bit_cast(u16, (__bf16)f);
}

// pack two f32 -> f16x2 dword
__device__ __forceinline__ u32 pkh(float a, float b) {
    h16x2 v; v[0] = (_Float16)a; v[1] = (_Float16)b;
    return __builtin_bit_cast(u32, v);
}
__device__ __forceinline__ float2 uph(u32 u) {
    h16x2 v = __builtin_bit_cast(h16x2, u);
    return make_float2((float)v[0], (float)v[1]);
}

__device__ __forceinline__ f32x4 mfma_bf16(u16x8 a, u16x8 b, f32x4 c) {
    return __builtin_amdgcn_mfma_f32_16x16x32_bf16(
        __builtin_bit_cast(b16x8, a), __builtin_bit_cast(b16x8, b), c, 0, 0, 0);
}

// swizzled index (u16 units) into a [16][64] bf16 tile, 128B rows.
#define SWZ(r, c) ((((r) * 64) + (c)) ^ (((r) & 7) << 3))

__device__ __forceinline__ void plane_interp(const float* __restrict__ g,
                                             float ca, float cb, float o[3]) {
    float pa = clampf((ca + 1.f) * (0.5f * 127.f), 0.f, 127.f);
    float pb = clampf((cb + 1.f) * (0.5f * 127.f), 0.f, 127.f);
    int la = (int)pa; if (la > 126) la = 126;
    int lb = (int)pb; if (lb > 126) lb = 126;
    float fa = pa - (float)la, fb = pb - (float)lb;
    float w00 = (1.f - fa) * (1.f - fb);
    float w01 = (1.f - fa) * fb;
    float w10 = fa * (1.f - fb);
    float w11 = fa * fb;
    const float* p = g + la * 128 + lb;
#pragma unroll
    for (int c = 0; c < 3; ++c) {
        const float* q = p + c * 16384;
        o[c] = q[0] * w00 + q[1] * w01 + q[128] * w10 + q[129] * w11;
    }
}

// ---- prep: pack weight B-fragments (bf16, per-lane layout) into workspace ----
// layout (u16x8 units): [0,256) Bw1 (nb*64+lane), [256,512) Bwc1,
//                       [512,640) Bw2 (ks*64+lane), [640,768) Bwc2
__global__ __launch_bounds__(256)
void prep_weights(const float* __restrict__ w1, const float* __restrict__ wc1,
                  const float* __restrict__ w2, const float* __restrict__ wc2,
                  u16* __restrict__ wsb)
{
    int idx = blockIdx.x * 256 + threadIdx.x;   // 0..6143
    if (idx >= 6144) return;
    int lane = (idx >> 3) & 63;
    int j = idx & 7;
    int c16 = lane & 15, kg = lane >> 4;
    float v;
    if (idx < 2048) {                       // Bw1
        int nb = idx >> 9;
        int k = kg * 8 + j;
        v = w1[k * 64 + nb * 16 + c16];
    } else if (idx < 4096) {                // Bwc1 (zero-pad k>=18)
        int nb = (idx - 2048) >> 9;
        int k = kg * 8 + j;
        v = (k < 18) ? wc1[k * 64 + nb * 16 + c16] : 0.f;
    } else if (idx < 5120) {                // Bw2
        int ks = (idx - 4096) >> 9;
        int k = ks * 32 + kg * 8 + j;
        v = w2[k * 16 + c16];
    } else {                                // Bwc2 (N padded to 16)
        int ks = (idx - 5120) >> 9;
        int k = ks * 32 + kg * 8 + j;
        v = (c16 < 3) ? wc2[k * 3 + c16] : 0.f;
    }
    wsb[idx] = f2bf(v);
}

// block = 1 ray, 4 waves; wave wv handles chunks {2wv, 2wv+1} of 16 samples
__global__ __launch_bounds__(256, 4)
void nerf_mfma(const float* __restrict__ rays_o,
               const float* __restrict__ rays_d,
               const float* __restrict__ bg_color,
               const float* __restrict__ plane01,
               const float* __restrict__ plane02,
               const float* __restrict__ plane12,
               const float* __restrict__ features,
               const float* __restrict__ w1, const float* __restrict__ b1,
               const float* __restrict__ w2, const float* __restrict__ b2,
               const float* __restrict__ wc1, const float* __restrict__ bc1,
               const float* __restrict__ wc2, const float* __restrict__ bc2,
               const float* __restrict__ aabb,
               float* __restrict__ out,
               const u16* __restrict__ wsb, int use_ws)
{
    __shared__ __align__(16) u32x4 s_cw[128];           // trilinear corner weights (f16x2 x4)
    __shared__ u32   s_fb[128];                         // cell base offsets
    __shared__ __align__(16) u16  s_trans[4][16 * 64];  // per-wave h/h2 transpose tile
    __shared__ __align__(16) u16  s_cin[4][16 * 64];    // per-wave color-MLP A tile
    __shared__ float s_tau[128];
    __shared__ float s_rgb[3][128];

    const int tid  = threadIdx.x;
    const int wv   = tid >> 6;
    const int lane = tid & 63;
    const int c16  = lane & 15;
    const int kg   = lane >> 4;
    const int ray  = blockIdx.x;

    // ---- weight B-fragments (VGPR-resident) ----
    u16x8 Bw1[4], Bwc1[4], Bw2[2], Bwc2[2];
    if (use_ws) {
        const u16x8* wf = (const u16x8*)wsb;
#pragma unroll
        for (int nb = 0; nb < 4; ++nb) {
            Bw1[nb]  = wf[nb * 64 + lane];
            Bwc1[nb] = wf[256 + nb * 64 + lane];
        }
#pragma unroll
        for (int ks = 0; ks < 2; ++ks) {
            Bw2[ks]  = wf[512 + ks * 64 + lane];
            Bwc2[ks] = wf[640 + ks * 64 + lane];
        }
    } else {
#pragma unroll
        for (int nb = 0; nb < 4; ++nb)
#pragma unroll
            for (int j = 0; j < 8; ++j) {
                int k = kg * 8 + j;
                Bw1[nb][j]  = f2bf(w1[k * 64 + nb * 16 + c16]);
                Bwc1[nb][j] = f2bf(k < 18 ? wc1[k * 64 + nb * 16 + c16] : 0.f);
            }
#pragma unroll
        for (int ks = 0; ks < 2; ++ks)
#pragma unroll
            for (int j = 0; j < 8; ++j) {
                int k = ks * 32 + kg * 8 + j;
                Bw2[ks][j]  = f2bf(w2[k * 16 + c16]);
                Bwc2[ks][j] = f2bf(c16 < 3 ? wc2[k * 3 + c16] : 0.f);
            }
    }
    float b1v[4], bc1v[4];
#pragma unroll
    for (int nb = 0; nb < 4; ++nb) {
        b1v[nb]  = b1[nb * 16 + c16];
        bc1v[nb] = bc1[nb * 16 + c16];
    }
    float b2v  = b2[c16];
    float bc2v = (c16 < 3) ? bc2[c16] : 0.f;

    // ---- per-ray setup ----
    float ox = rays_o[ray * 3 + 0], oy = rays_o[ray * 3 + 1], oz = rays_o[ray * 3 + 2];
    float dx = rays_d[ray * 3 + 0], dy = rays_d[ray * 3 + 1], dz = rays_d[ray * 3 + 2];
    float rn = rsqrtf(dx * dx + dy * dy + dz * dz);
    dx *= rn; dy *= rn; dz *= rn;

    float lo0 = aabb[0], lo1 = aabb[1], lo2 = aabb[2];
    float hi0 = aabb[3], hi1 = aabb[4], hi2 = aabb[5];

    float invx = 1.f / dx, invy = 1.f / dy, invz = 1.f / dz;
    float tx0 = (lo0 - ox) * invx, tx1 = (hi0 - ox) * invx;
    float ty0 = (lo1 - oy) * invy, ty1 = (hi1 - oy) * invy;
    float tz0 = (lo2 - oz) * invz, tz1 = (hi2 - oz) * invz;
    float tnear = fmaxf(fmaxf(fminf(tx0, tx1), fminf(ty0, ty1)), fminf(tz0, tz1));
    tnear = fmaxf(tnear, 0.f);
    float tfar = fminf(fminf(fmaxf(tx0, tx1), fmaxf(ty0, ty1)), fmaxf(tz0, tz1));
    tfar = fmaxf(tfar, tnear);
    float delta = (tfar - tnear) * (1.f / (float)NS);

    // ---- coordinate phase: threads 0..127 compute 1 sample each ----
    if (tid < 128) {
        int s = tid;
        float t = tnear + delta * ((float)s + 0.5f);
        float px = ox + dx * t, py = oy + dy * t, pz = oz + dz * t;
        px = (px - lo0) * (2.f / (hi0 - lo0)) - 1.f;
        py = (py - lo1) * (2.f / (hi1 - lo1)) - 1.f;
        pz = (pz - lo2) * (2.f / (hi2 - lo2)) - 1.f;

        float p01[3], p02[3], p12[3];
        plane_interp(plane01, px, py, p01);
        plane_interp(plane02, px, pz, p02);
        plane_interp(plane12, py, pz, p12);
        float gx = p01[0] * p02[0] * p12[0];
        float gy = p01[1] * p02[1] * p12[1];
        float gz = p01[2] * p02[2] * p12[2];

        float qx = clampf((gx + 1.f) * (0.5f * 63.f), 0.f, 63.f);
        float qy = clampf((gy + 1.f) * (0.5f * 63.f), 0.f, 63.f);
        float qz = clampf((gz + 1.f) * (0.5f * 63.f), 0.f, 63.f);
        int ixg = (int)qx; if (ixg > 62) ixg = 62;
        int iyg = (int)qy; if (iyg > 62) iyg = 62;
        int izg = (int)qz; if (izg > 62) izg = 62;
        float fx = qx - (float)ixg, fy = qy - (float)iyg, fz = qz - (float)izg;
        float wx0 = 1.f - fx, wy0 = 1.f - fy, wz0 = 1.f - fz;
        u32x4 cw;
        cw[0] = pkh(wx0 * wy0 * wz0, wx0 * wy0 * fz);
        cw[1] = pkh(wx0 * fy  * wz0, wx0 * fy  * fz);
        cw[2] = pkh(fx  * wy0 * wz0, fx  * wy0 * fz);
        cw[3] = pkh(fx  * fy  * wz0, fx  * fy  * fz);
        s_cw[s] = cw;
        s_fb[s] = (u32)(ixg * 4096 + iyg * 64 + izg);
    }

    // ---- init this wave's cin tile: zero (pads k=18..31), dirs in cols 0..2 ----
    {
        u32x4 z4 = {0, 0, 0, 0};
        u32x4* zp = (u32x4*)s_cin[wv];
#pragma unroll
        for (int i = lane; i < 128; i += 64) zp[i] = z4;
        if (lane < 16) {
            s_cin[wv][SWZ(lane, 0)] = f2bf(dx);
            s_cin[wv][SWZ(lane, 1)] = f2bf(dy);
            s_cin[wv][SWZ(lane, 2)] = f2bf(dz);
        }
    }
    __syncthreads();

    // ---- 2 chunks of 16 samples per wave ----
#pragma unroll
    for (int cc = 0; cc < 2; ++cc) {
        const int c = wv * 2 + cc;
        u32x4 cwp = s_cw[c * 16 + c16];
        u32 fb = s_fb[c * 16 + c16];
        float2 w01p = uph(cwp[0]);
        float2 w23p = uph(cwp[1]);
        float2 w45p = uph(cwp[2]);
        float2 w67p = uph(cwp[3]);
        const float* fbase = features + fb;

        u16x8 a1;
#pragma unroll
        for (int j = 0; j < 8; ++j) {
            const float* f = fbase + (size_t)(kg * 8 + j) * 262144;
            float v = w01p.x * f[0]    + w01p.y * f[1]
                    + w23p.x * f[64]   + w23p.y * f[65]
                    + w45p.x * f[4096] + w45p.y * f[4097]
                    + w67p.x * f[4160] + w67p.y * f[4161];
            a1[j] = f2bf(v);
        }

        // GEMM1: h[16x64] = A1 @ w1 + b1
        f32x4 acc[4];
#pragma unroll
        for (int nb = 0; nb < 4; ++nb) {
            f32x4 ci; ci[0] = ci[1] = ci[2] = ci[3] = b1v[nb];
            acc[nb] = mfma_bf16(a1, Bw1[nb], ci);
        }
#pragma unroll
        for (int nb = 0; nb < 4; ++nb)
#pragma unroll
            for (int q = 0; q < 4; ++q) {
                int r = kg * 4 + q;
                s_trans[wv][SWZ(r, nb * 16 + c16)] = f2bf(fmaxf(acc[nb][q], 0.f));
            }

        // GEMM2: so[16x16] = relu(h) @ w2 + b2
        f32x4 acc2; acc2[0] = acc2[1] = acc2[2] = acc2[3] = b2v;
#pragma unroll
        for (int ks = 0; ks < 2; ++ks) {
            u16x8 a2 = *(const u16x8*)&s_trans[wv][SWZ(c16, ks * 32 + kg * 8)];
            acc2 = mfma_bf16(a2, Bw2[ks], acc2);
        }

        // density (col 0) -> tau ; so[1:16] -> cin cols 3..17
        if (c16 == 0) {
#pragma unroll
            for (int q = 0; q < 4; ++q) {
                float d = __expf(clampf(acc2[q], -15.f, 15.f));
                s_tau[c * 16 + kg * 4 + q] = d * delta;
            }
        } else {
#pragma unroll
            for (int q = 0; q < 4; ++q) {
                int r = kg * 4 + q;
                s_cin[wv][SWZ(r, c16 + 2)] = f2bf(acc2[q]);
            }
        }

        // GEMM3: h2[16x64] = cin @ wc1 + bc1
        u16x8 a3 = *(const u16x8*)&s_cin[wv][SWZ(c16, kg * 8)];
        f32x4 acc3[4];
#pragma unroll
        for (int nb = 0; nb < 4; ++nb) {
            f32x4 ci; ci[0] = ci[1] = ci[2] = ci[3] = bc1v[nb];
            acc3[nb] = mfma_bf16(a3, Bwc1[nb], ci);
        }
#pragma unroll
        for (int nb = 0; nb < 4; ++nb)
#pragma unroll
            for (int q = 0; q < 4; ++q) {
                int r = kg * 4 + q;
                s_trans[wv][SWZ(r, nb * 16 + c16)] = f2bf(fmaxf(acc3[nb][q], 0.f));
            }

        // GEMM4: rgb[16x3] = relu(h2) @ wc2 + bc2
        f32x4 acc4; acc4[0] = acc4[1] = acc4[2] = acc4[3] = bc2v;
#pragma unroll
        for (int ks = 0; ks < 2; ++ks) {
            u16x8 a4 = *(const u16x8*)&s_trans[wv][SWZ(c16, ks * 32 + kg * 8)];
            acc4 = mfma_bf16(a4, Bwc2[ks], acc4);
        }
        if (c16 < 3) {
#pragma unroll
            for (int q = 0; q < 4; ++q) {
                float sg = 1.f / (1.f + __expf(-acc4[q]));
                s_rgb[c16][c * 16 + kg * 4 + q] = sg;
            }
        }
    }
    __syncthreads();

    // ---- integration on wave 0 (2 samples per lane) ----
    if (wv == 0) {
        float t0 = s_tau[lane];
        float t1 = s_tau[64 + lane];
        float x0 = t0, x1 = t1;
#pragma unroll
        for (int off = 1; off < 64; off <<= 1) {
            float y = __shfl_up(x0, off);
            if (lane >= off) x0 += y;
        }
        float tot0 = __shfl(x0, 63);
#pragma unroll
        for (int off = 1; off < 64; off <<= 1) {
            float y = __shfl_up(x1, off);
            if (lane >= off) x1 += y;
        }
        x1 += tot0;

        float w0 = __expf(t0 - x0) * (1.f - __expf(-t0));
        float w1s = __expf(t1 - x1) * (1.f - __expf(-t1));

        float v0 = w0 * s_rgb[0][lane] + w1s * s_rgb[0][64 + lane];
        float v1 = w0 * s_rgb[1][lane] + w1s * s_rgb[1][64 + lane];
        float v2 = w0 * s_rgb[2][lane] + w1s * s_rgb[2][64 + lane];
        float v3 = w0 + w1s;
#pragma unroll
        for (int off = 32; off; off >>= 1) {
            v0 += __shfl_xor(v0, off);
            v1 += __shfl_xor(v1, off);
            v2 += __shfl_xor(v2, off);
            v3 += __shfl_xor(v3, off);
        }
        if (lane == 0) {
            float bg = bg_color[0];
            out[ray * 3 + 0] = v0 + (1.f - v3) * bg;
            out[ray * 3 + 1] = v1 + (1.f - v3) * bg;
            out[ray * 3 + 2] = v2 + (1.f - v3) * bg;
        }
    }
}

extern "C" void kernel_launch(void* const* d_in, const int* in_sizes, int n_in,
                              void* d_out, int out_size, void* d_ws, size_t ws_size,
                              hipStream_t stream) {
    const float* rays_o  = (const float*)d_in[0];
    const float* rays_d  = (const float*)d_in[1];
    const float* bg      = (const float*)d_in[2];
    const float* p01     = (const float*)d_in[3];
    const float* p02     = (const float*)d_in[4];
    const float* p12     = (const float*)d_in[5];
    const float* feats   = (const float*)d_in[6];
    const float* w1      = (const float*)d_in[7];
    const float* b1      = (const float*)d_in[8];
    const float* w2      = (const float*)d_in[9];
    const float* b2      = (const float*)d_in[10];
    const float* wc1     = (const float*)d_in[11];
    const float* bc1     = (const float*)d_in[12];
    const float* wc2     = (const float*)d_in[13];
    const float* bc2     = (const float*)d_in[14];
    const float* aabb    = (const float*)d_in[15];
    float* out = (float*)d_out;

    const int use_ws = (ws_size >= 6144 * sizeof(u16)) ? 1 : 0;
    u16* wsb = (u16*)d_ws;
    if (use_ws) {
        prep_weights<<<24, 256, 0, stream>>>(w1, wc1, w2, wc2, wsb);
    }
    nerf_mfma<<<NRAYS, 256, 0, stream>>>(rays_o, rays_d, bg, p01, p02, p12, feats,
                                         w1, b1, w2, b2, wc1, bc1, wc2, bc2, aabb, out,
                                         wsb, use_ws);
}

// Round 7
// 123.320 us; speedup vs baseline: 1.7438x; 1.7438x over previous
//
#include <hip/hip_runtime.h>

#define NS 128
#define NRAYS 8192

typedef unsigned short u16;
typedef unsigned int   u32;
typedef unsigned short u16x8 __attribute__((ext_vector_type(8)));
typedef __bf16 b16x8 __attribute__((ext_vector_type(8)));
typedef float f32x4 __attribute__((ext_vector_type(4)));
typedef _Float16 h16x2 __attribute__((ext_vector_type(2)));
typedef unsigned int u32x4 __attribute__((ext_vector_type(4)));

__device__ __forceinline__ float clampf(float x, float lo, float hi) {
    return fminf(fmaxf(x, lo), hi);
}

// f32 -> bf16 bits via native cast (single v_cvt, RNE)
__device__ __forceinline__ u16 f2bf(float f) {
    return __builtin_bit_cast(u16, (__bf16)f);
}

// pack two f32 -> f16x2 dword
__device__ __forceinline__ u32 pkh(float a, float b) {
    h16x2 v; v[0] = (_Float16)a; v[1] = (_Float16)b;
    return __builtin_bit_cast(u32, v);
}
__device__ __forceinline__ float2 uph(u32 u) {
    h16x2 v = __builtin_bit_cast(h16x2, u);
    return make_float2((float)v[0], (float)v[1]);
}

__device__ __forceinline__ f32x4 mfma_bf16(u16x8 a, u16x8 b, f32x4 c) {
    return __builtin_amdgcn_mfma_f32_16x16x32_bf16(
        __builtin_bit_cast(b16x8, a), __builtin_bit_cast(b16x8, b), c, 0, 0, 0);
}

// swizzled index (u16 units) into a [16][64] bf16 tile, 128B rows.
#define SWZ(r, c) ((((r) * 64) + (c)) ^ (((r) & 7) << 3))

__device__ __forceinline__ void plane_interp(const float* __restrict__ g,
                                             float ca, float cb, float o[3]) {
    float pa = clampf((ca + 1.f) * (0.5f * 127.f), 0.f, 127.f);
    float pb = clampf((cb + 1.f) * (0.5f * 127.f), 0.f, 127.f);
    int la = (int)pa; if (la > 126) la = 126;
    int lb = (int)pb; if (lb > 126) lb = 126;
    float fa = pa - (float)la, fb = pb - (float)lb;
    float w00 = (1.f - fa) * (1.f - fb);
    float w01 = (1.f - fa) * fb;
    float w10 = fa * (1.f - fb);
    float w11 = fa * fb;
    const float* p = g + la * 128 + lb;
#pragma unroll
    for (int c = 0; c < 3; ++c) {
        const float* q = p + c * 16384;
        o[c] = q[0] * w00 + q[1] * w01 + q[128] * w10 + q[129] * w11;
    }
}

// ---- prep: pack weight B-fragments (bf16, per-lane layout) into workspace ----
// layout (u16x8 units): [0,256) Bw1 (nb*64+lane), [256,512) Bwc1,
//                       [512,640) Bw2 (ks*64+lane), [640,768) Bwc2
__global__ __launch_bounds__(256)
void prep_weights(const float* __restrict__ w1, const float* __restrict__ wc1,
                  const float* __restrict__ w2, const float* __restrict__ wc2,
                  u16* __restrict__ wsb)
{
    int idx = blockIdx.x * 256 + threadIdx.x;   // 0..6143
    if (idx >= 6144) return;
    int lane = (idx >> 3) & 63;
    int j = idx & 7;
    int c16 = lane & 15, kg = lane >> 4;
    float v;
    if (idx < 2048) {                       // Bw1
        int nb = idx >> 9;
        int k = kg * 8 + j;
        v = w1[k * 64 + nb * 16 + c16];
    } else if (idx < 4096) {                // Bwc1 (zero-pad k>=18)
        int nb = (idx - 2048) >> 9;
        int k = kg * 8 + j;
        v = (k < 18) ? wc1[k * 64 + nb * 16 + c16] : 0.f;
    } else if (idx < 5120) {                // Bw2
        int ks = (idx - 4096) >> 9;
        int k = ks * 32 + kg * 8 + j;
        v = w2[k * 16 + c16];
    } else {                                // Bwc2 (N padded to 16)
        int ks = (idx - 5120) >> 9;
        int k = ks * 32 + kg * 8 + j;
        v = (c16 < 3) ? wc2[k * 3 + c16] : 0.f;
    }
    wsb[idx] = f2bf(v);
}

// block = 1 ray, 4 waves; wave wv handles chunks {2wv, 2wv+1} of 16 samples.
// NOTE: no min-waves arg — launch_bounds(256,4) capped VGPR at 64 and spilled
// (round 6: FETCH 190MB, WRITE 303MB). Plain (256) gives ~112 VGPR, no spill.
__global__ __launch_bounds__(256)
void nerf_mfma(const float* __restrict__ rays_o,
               const float* __restrict__ rays_d,
               const float* __restrict__ bg_color,
               const float* __restrict__ plane01,
               const float* __restrict__ plane02,
               const float* __restrict__ plane12,
               const float* __restrict__ features,
               const float* __restrict__ w1, const float* __restrict__ b1,
               const float* __restrict__ w2, const float* __restrict__ b2,
               const float* __restrict__ wc1, const float* __restrict__ bc1,
               const float* __restrict__ wc2, const float* __restrict__ bc2,
               const float* __restrict__ aabb,
               float* __restrict__ out,
               const u16* __restrict__ wsb, int use_ws)
{
    __shared__ __align__(16) u32x4 s_cw[128];           // trilinear corner weights (f16x2 x4)
    __shared__ u32   s_fb[128];                         // cell base offsets
    __shared__ __align__(16) u16  s_trans[4][16 * 64];  // per-wave h/h2 transpose tile
    __shared__ __align__(16) u16  s_cin[4][16 * 64];    // per-wave color-MLP A tile
    __shared__ float s_tau[128];
    __shared__ float s_rgb[3][128];

    const int tid  = threadIdx.x;
    const int wv   = tid >> 6;
    const int lane = tid & 63;
    const int c16  = lane & 15;
    const int kg   = lane >> 4;
    const int ray  = blockIdx.x;

    // ---- weight B-fragments (VGPR-resident) ----
    u16x8 Bw1[4], Bwc1[4], Bw2[2], Bwc2[2];
    if (use_ws) {
        const u16x8* wf = (const u16x8*)wsb;
#pragma unroll
        for (int nb = 0; nb < 4; ++nb) {
            Bw1[nb]  = wf[nb * 64 + lane];
            Bwc1[nb] = wf[256 + nb * 64 + lane];
        }
#pragma unroll
        for (int ks = 0; ks < 2; ++ks) {
            Bw2[ks]  = wf[512 + ks * 64 + lane];
            Bwc2[ks] = wf[640 + ks * 64 + lane];
        }
    } else {
#pragma unroll
        for (int nb = 0; nb < 4; ++nb)
#pragma unroll
            for (int j = 0; j < 8; ++j) {
                int k = kg * 8 + j;
                Bw1[nb][j]  = f2bf(w1[k * 64 + nb * 16 + c16]);
                Bwc1[nb][j] = f2bf(k < 18 ? wc1[k * 64 + nb * 16 + c16] : 0.f);
            }
#pragma unroll
        for (int ks = 0; ks < 2; ++ks)
#pragma unroll
            for (int j = 0; j < 8; ++j) {
                int k = ks * 32 + kg * 8 + j;
                Bw2[ks][j]  = f2bf(w2[k * 16 + c16]);
                Bwc2[ks][j] = f2bf(c16 < 3 ? wc2[k * 3 + c16] : 0.f);
            }
    }
    float b1v[4], bc1v[4];
#pragma unroll
    for (int nb = 0; nb < 4; ++nb) {
        b1v[nb]  = b1[nb * 16 + c16];
        bc1v[nb] = bc1[nb * 16 + c16];
    }
    float b2v  = b2[c16];
    float bc2v = (c16 < 3) ? bc2[c16] : 0.f;

    // ---- per-ray setup ----
    float ox = rays_o[ray * 3 + 0], oy = rays_o[ray * 3 + 1], oz = rays_o[ray * 3 + 2];
    float dx = rays_d[ray * 3 + 0], dy = rays_d[ray * 3 + 1], dz = rays_d[ray * 3 + 2];
    float rn = rsqrtf(dx * dx + dy * dy + dz * dz);
    dx *= rn; dy *= rn; dz *= rn;

    float lo0 = aabb[0], lo1 = aabb[1], lo2 = aabb[2];
    float hi0 = aabb[3], hi1 = aabb[4], hi2 = aabb[5];

    float invx = 1.f / dx, invy = 1.f / dy, invz = 1.f / dz;
    float tx0 = (lo0 - ox) * invx, tx1 = (hi0 - ox) * invx;
    float ty0 = (lo1 - oy) * invy, ty1 = (hi1 - oy) * invy;
    float tz0 = (lo2 - oz) * invz, tz1 = (hi2 - oz) * invz;
    float tnear = fmaxf(fmaxf(fminf(tx0, tx1), fminf(ty0, ty1)), fminf(tz0, tz1));
    tnear = fmaxf(tnear, 0.f);
    float tfar = fminf(fminf(fmaxf(tx0, tx1), fmaxf(ty0, ty1)), fmaxf(tz0, tz1));
    tfar = fmaxf(tfar, tnear);
    float delta = (tfar - tnear) * (1.f / (float)NS);

    // ---- coordinate phase: threads 0..127 compute 1 sample each ----
    if (tid < 128) {
        int s = tid;
        float t = tnear + delta * ((float)s + 0.5f);
        float px = ox + dx * t, py = oy + dy * t, pz = oz + dz * t;
        px = (px - lo0) * (2.f / (hi0 - lo0)) - 1.f;
        py = (py - lo1) * (2.f / (hi1 - lo1)) - 1.f;
        pz = (pz - lo2) * (2.f / (hi2 - lo2)) - 1.f;

        float p01[3], p02[3], p12[3];
        plane_interp(plane01, px, py, p01);
        plane_interp(plane02, px, pz, p02);
        plane_interp(plane12, py, pz, p12);
        float gx = p01[0] * p02[0] * p12[0];
        float gy = p01[1] * p02[1] * p12[1];
        float gz = p01[2] * p02[2] * p12[2];

        float qx = clampf((gx + 1.f) * (0.5f * 63.f), 0.f, 63.f);
        float qy = clampf((gy + 1.f) * (0.5f * 63.f), 0.f, 63.f);
        float qz = clampf((gz + 1.f) * (0.5f * 63.f), 0.f, 63.f);
        int ixg = (int)qx; if (ixg > 62) ixg = 62;
        int iyg = (int)qy; if (iyg > 62) iyg = 62;
        int izg = (int)qz; if (izg > 62) izg = 62;
        float fx = qx - (float)ixg, fy = qy - (float)iyg, fz = qz - (float)izg;
        float wx0 = 1.f - fx, wy0 = 1.f - fy, wz0 = 1.f - fz;
        u32x4 cw;
        cw[0] = pkh(wx0 * wy0 * wz0, wx0 * wy0 * fz);
        cw[1] = pkh(wx0 * fy  * wz0, wx0 * fy  * fz);
        cw[2] = pkh(fx  * wy0 * wz0, fx  * wy0 * fz);
        cw[3] = pkh(fx  * fy  * wz0, fx  * fy  * fz);
        s_cw[s] = cw;
        s_fb[s] = (u32)(ixg * 4096 + iyg * 64 + izg);
    }

    // ---- init this wave's cin tile: zero (pads k=18..31), dirs in cols 0..2 ----
    {
        u32x4 z4 = {0, 0, 0, 0};
        u32x4* zp = (u32x4*)s_cin[wv];
#pragma unroll
        for (int i = lane; i < 128; i += 64) zp[i] = z4;
        if (lane < 16) {
            s_cin[wv][SWZ(lane, 0)] = f2bf(dx);
            s_cin[wv][SWZ(lane, 1)] = f2bf(dy);
            s_cin[wv][SWZ(lane, 2)] = f2bf(dz);
        }
    }
    __syncthreads();

    // ---- 2 chunks of 16 samples per wave ----
#pragma unroll
    for (int cc = 0; cc < 2; ++cc) {
        const int c = wv * 2 + cc;
        u32x4 cwp = s_cw[c * 16 + c16];
        u32 fb = s_fb[c * 16 + c16];
        float2 w01p = uph(cwp[0]);
        float2 w23p = uph(cwp[1]);
        float2 w45p = uph(cwp[2]);
        float2 w67p = uph(cwp[3]);
        const float* fbase = features + fb;

        u16x8 a1;
#pragma unroll
        for (int j = 0; j < 8; ++j) {
            const float* f = fbase + (size_t)(kg * 8 + j) * 262144;
            float v = w01p.x * f[0]    + w01p.y * f[1]
                    + w23p.x * f[64]   + w23p.y * f[65]
                    + w45p.x * f[4096] + w45p.y * f[4097]
                    + w67p.x * f[4160] + w67p.y * f[4161];
            a1[j] = f2bf(v);
        }

        // GEMM1: h[16x64] = A1 @ w1 + b1
        f32x4 acc[4];
#pragma unroll
        for (int nb = 0; nb < 4; ++nb) {
            f32x4 ci; ci[0] = ci[1] = ci[2] = ci[3] = b1v[nb];
            acc[nb] = mfma_bf16(a1, Bw1[nb], ci);
        }
#pragma unroll
        for (int nb = 0; nb < 4; ++nb)
#pragma unroll
            for (int q = 0; q < 4; ++q) {
                int r = kg * 4 + q;
                s_trans[wv][SWZ(r, nb * 16 + c16)] = f2bf(fmaxf(acc[nb][q], 0.f));
            }

        // GEMM2: so[16x16] = relu(h) @ w2 + b2
        f32x4 acc2; acc2[0] = acc2[1] = acc2[2] = acc2[3] = b2v;
#pragma unroll
        for (int ks = 0; ks < 2; ++ks) {
            u16x8 a2 = *(const u16x8*)&s_trans[wv][SWZ(c16, ks * 32 + kg * 8)];
            acc2 = mfma_bf16(a2, Bw2[ks], acc2);
        }

        // density (col 0) -> tau ; so[1:16] -> cin cols 3..17
        if (c16 == 0) {
#pragma unroll
            for (int q = 0; q < 4; ++q) {
                float d = __expf(clampf(acc2[q], -15.f, 15.f));
                s_tau[c * 16 + kg * 4 + q] = d * delta;
            }
        } else {
#pragma unroll
            for (int q = 0; q < 4; ++q) {
                int r = kg * 4 + q;
                s_cin[wv][SWZ(r, c16 + 2)] = f2bf(acc2[q]);
            }
        }

        // GEMM3: h2[16x64] = cin @ wc1 + bc1
        u16x8 a3 = *(const u16x8*)&s_cin[wv][SWZ(c16, kg * 8)];
        f32x4 acc3[4];
#pragma unroll
        for (int nb = 0; nb < 4; ++nb) {
            f32x4 ci; ci[0] = ci[1] = ci[2] = ci[3] = bc1v[nb];
            acc3[nb] = mfma_bf16(a3, Bwc1[nb], ci);
        }
#pragma unroll
        for (int nb = 0; nb < 4; ++nb)
#pragma unroll
            for (int q = 0; q < 4; ++q) {
                int r = kg * 4 + q;
                s_trans[wv][SWZ(r, nb * 16 + c16)] = f2bf(fmaxf(acc3[nb][q], 0.f));
            }

        // GEMM4: rgb[16x3] = relu(h2) @ wc2 + bc2
        f32x4 acc4; acc4[0] = acc4[1] = acc4[2] = acc4[3] = bc2v;
#pragma unroll
        for (int ks = 0; ks < 2; ++ks) {
            u16x8 a4 = *(const u16x8*)&s_trans[wv][SWZ(c16, ks * 32 + kg * 8)];
            acc4 = mfma_bf16(a4, Bwc2[ks], acc4);
        }
        if (c16 < 3) {
#pragma unroll
            for (int q = 0; q < 4; ++q) {
                float sg = 1.f / (1.f + __expf(-acc4[q]));
                s_rgb[c16][c * 16 + kg * 4 + q] = sg;
            }
        }
    }
    __syncthreads();

    // ---- integration on wave 0 (2 samples per lane) ----
    if (wv == 0) {
        float t0 = s_tau[lane];
        float t1 = s_tau[64 + lane];
        float x0 = t0, x1 = t1;
#pragma unroll
        for (int off = 1; off < 64; off <<= 1) {
            float y = __shfl_up(x0, off);
            if (lane >= off) x0 += y;
        }
        float tot0 = __shfl(x0, 63);
#pragma unroll
        for (int off = 1; off < 64; off <<= 1) {
            float y = __shfl_up(x1, off);
            if (lane >= off) x1 += y;
        }
        x1 += tot0;

        float w0 = __expf(t0 - x0) * (1.f - __expf(-t0));
        float w1s = __expf(t1 - x1) * (1.f - __expf(-t1));

        float v0 = w0 * s_rgb[0][lane] + w1s * s_rgb[0][64 + lane];
        float v1 = w0 * s_rgb[1][lane] + w1s * s_rgb[1][64 + lane];
        float v2 = w0 * s_rgb[2][lane] + w1s * s_rgb[2][64 + lane];
        float v3 = w0 + w1s;
#pragma unroll
        for (int off = 32; off; off >>= 1) {
            v0 += __shfl_xor(v0, off);
            v1 += __shfl_xor(v1, off);
            v2 += __shfl_xor(v2, off);
            v3 += __shfl_xor(v3, off);
        }
        if (lane == 0) {
            float bg = bg_color[0];
            out[ray * 3 + 0] = v0 + (1.f - v3) * bg;
            out[ray * 3 + 1] = v1 + (1.f - v3) * bg;
            out[ray * 3 + 2] = v2 + (1.f - v3) * bg;
        }
    }
}

extern "C" void kernel_launch(void* const* d_in, const int* in_sizes, int n_in,
                              void* d_out, int out_size, void* d_ws, size_t ws_size,
                              hipStream_t stream) {
    const float* rays_o  = (const float*)d_in[0];
    const float* rays_d  = (const float*)d_in[1];
    const float* bg      = (const float*)d_in[2];
    const float* p01     = (const float*)d_in[3];
    const float* p02     = (const float*)d_in[4];
    const float* p12     = (const float*)d_in[5];
    const float* feats   = (const float*)d_in[6];
    const float* w1      = (const float*)d_in[7];
    const float* b1      = (const float*)d_in[8];
    const float* w2      = (const float*)d_in[9];
    const float* b2      = (const float*)d_in[10];
    const float* wc1     = (const float*)d_in[11];
    const float* bc1     = (const float*)d_in[12];
    const float* wc2     = (const float*)d_in[13];
    const float* bc2     = (const float*)d_in[14];
    const float* aabb    = (const float*)d_in[15];
    float* out = (float*)d_out;

    const int use_ws = (ws_size >= 6144 * sizeof(u16)) ? 1 : 0;
    u16* wsb = (u16*)d_ws;
    if (use_ws) {
        prep_weights<<<24, 256, 0, stream>>>(w1, wc1, w2, wc2, wsb);
    }
    nerf_mfma<<<NRAYS, 256, 0, stream>>>(rays_o, rays_d, bg, p01, p02, p12, feats,
                                         w1, b1, w2, b2, wc1, bc1, wc2, bc2, aabb, out,
                                         wsb, use_ws);
}